// Round 2
// baseline (386.075 us; speedup 1.0000x reference)
//
#include <hip/hip_runtime.h>
#include <stdint.h>

// Reference: B=16, C=256, L=16384, K=S=4 -> OL=4096. fp32 in, fp32 out.
#define B_    16
#define C_    256
#define L_    16384
#define OL_   4096
#define OT    16     // outputs per block
#define TL    64     // input l-positions per block (OT*4)
#define PITCH 68     // floats per LDS tile row (64 data + 4 pad; 272 B, 16B-aligned)

__global__ __launch_bounds__(256)
void havgpool_hyp_kernel(const float* __restrict__ x, float* __restrict__ out) {
    __shared__ float tile[C_ * PITCH];   // 68 KiB: [c][l] fp32
    __shared__ float p2[16 * TL];        // 4 KiB: per-(rowgroup, l) sum(x^2) partials
    __shared__ float sA1[TL];            // per-l combine coefficient
    __shared__ float sW[4 * OT];         // cross-wave mK2 partials
    __shared__ float sInvm[OT];          // per-o final scale

    const int t     = threadIdx.x;
    const int otile = blockIdx.x;        // 0..255
    const int b     = blockIdx.y;        // 0..15
    const int l0    = otile * TL;
    const int o0    = otile * OT;

    const int j     = t & 15;            // l-quad 0..15 (l = 4j..4j+3)
    const int rbase = t >> 4;            // 0..15

    // ---- Phase A: global -> LDS, accumulate per-l sum_c(x^2) partials in flight.
    // Wave coalescing: 16 consecutive lanes cover one row's 256 B segment.
    float acc[4] = {0.f, 0.f, 0.f, 0.f};
    const float* src = x + ((size_t)b * C_ * L_ + l0 + 4 * j);
    #pragma unroll
    for (int it = 0; it < 16; ++it) {
        const int r = it * 16 + rbase;                       // channel 0..255
        const float4 v = *(const float4*)(src + (size_t)r * L_);
        acc[0] += v.x * v.x;
        acc[1] += v.y * v.y;
        acc[2] += v.z * v.z;
        acc[3] += v.w * v.w;
        *(float4*)&tile[r * PITCH + 4 * j] = v;
    }
    #pragma unroll
    for (int e = 0; e < 4; ++e) p2[rbase * TL + 4 * j + e] = acc[e];

    __syncthreads();

    // ---- per-l scalars (wave 0): x2 -> gamma -> a1[l] = 2*gamma*inv1/G
    if (t < TL) {
        float x2 = 0.f;
        #pragma unroll
        for (int k = 0; k < 16; ++k) x2 += p2[k * TL + t];   // bank = t%32: 2-way, free
        const float inv1 = 1.0f / (1.0f + x2);
        const float xk2  = 4.0f * x2 * inv1 * inv1;          // sum_c xK^2
        const float g    = rsqrtf(fmaxf(1.0f - xk2, 1e-7f)); // gamma
        float G = g;                                         // sum over 4-window
        G += __shfl_xor(G, 1, 64);
        G += __shfl_xor(G, 2, 64);
        sA1[t] = 2.0f * g * inv1 / G;
    }
    __syncthreads();

    // ---- Phase B: thread = channel; 16 mK values from the LDS row
    const int c = t;
    float mK[OT];
    #pragma unroll
    for (int o = 0; o < OT; ++o) {
        const float4 v = *(const float4*)&tile[c * PITCH + 4 * o];
        mK[o] = v.x * sA1[4*o] + v.y * sA1[4*o+1] + v.z * sA1[4*o+2] + v.w * sA1[4*o+3];
    }

    // mK2[o] = sum_c mK^2: wave butterfly + cross-wave via LDS
    const int lane = t & 63;
    const int w    = t >> 6;
    #pragma unroll
    for (int o = 0; o < OT; ++o) {
        float v = mK[o] * mK[o];
        #pragma unroll
        for (int off = 32; off >= 1; off >>= 1) v += __shfl_xor(v, off, 64);
        if (lane == o) sW[w * OT + o] = v;
    }
    __syncthreads();
    if (t < OT) {
        const float m2 = sW[t] + sW[OT + t] + sW[2 * OT + t] + sW[3 * OT + t];
        sInvm[t] = 1.0f / (1.0f + sqrtf(fmaxf(1.0f - m2, 1e-7f)));
    }
    __syncthreads();

    // ---- Phase C: scale and store 64 B contiguous per thread (fp32 out)
    float* op = out + ((size_t)(b * C_ + c) * OL_ + o0);
    #pragma unroll
    for (int q = 0; q < 4; ++q) {
        float4 ov;
        ov.x = mK[4*q + 0] * sInvm[4*q + 0];
        ov.y = mK[4*q + 1] * sInvm[4*q + 1];
        ov.z = mK[4*q + 2] * sInvm[4*q + 2];
        ov.w = mK[4*q + 3] * sInvm[4*q + 3];
        *(float4*)(op + 4 * q) = ov;
    }
}

extern "C" void kernel_launch(void* const* d_in, const int* in_sizes, int n_in,
                              void* d_out, int out_size, void* d_ws, size_t ws_size,
                              hipStream_t stream) {
    const float* x = (const float*)d_in[0];
    float* out = (float*)d_out;
    dim3 grid(OL_ / OT, B_);   // 256 o-tiles x 16 batches
    havgpool_hyp_kernel<<<grid, 256, 0, stream>>>(x, out);
}

// Round 3
// 381.692 us; speedup vs baseline: 1.0115x; 1.0115x over previous
//
#include <hip/hip_runtime.h>
#include <stdint.h>

// Reference: B=16, C=256, L=16384, K=S=4 -> OL=4096. fp32 in, fp32 out.
// Key fact: thread t (j = t&15) owns l-quad 4j..4j+3 == the FULL window of
// output o0+j, for its 16 channels -> mK is computed entirely in registers.
#define B_    16
#define C_    256
#define L_    16384
#define OL_   4096
#define OT    16     // outputs per block
#define TL    64     // input l-positions per block (OT*4)

__global__ __launch_bounds__(256, 4)
void havgpool_hyp_kernel(const float* __restrict__ x, float* __restrict__ out) {
    __shared__ float sP[4][TL];    // per-wave sum_c(x^2) partials   (1 KiB)
    __shared__ float sA1[TL];      // per-l combine coefficient
    __shared__ float sQ[4][OT];    // per-wave mK2 partials
    __shared__ float sInvm[OT];    // per-o final scale

    const int t     = threadIdx.x;
    const int otile = blockIdx.x;      // 0..255
    const int b     = blockIdx.y;      // 0..15
    const int j     = t & 15;          // output (and l-quad) index 0..15
    const int lane  = t & 63;
    const int w     = t >> 6;
    const int rbase = t >> 4;          // channel-group 0..15

    // ---- Load 16 channels x 4 l into registers; squares accumulated in flight.
    // Wave coalescing: 16 consecutive lanes cover one row's 256 B segment.
    const float* src = x + ((size_t)b * C_ * L_ + (size_t)otile * TL + 4 * j);
    float4 v[16];
    float a0 = 0.f, a1 = 0.f, a2 = 0.f, a3 = 0.f;
    #pragma unroll
    for (int it = 0; it < 16; ++it) {
        v[it] = *(const float4*)(src + (size_t)(it * 16 + rbase) * L_);
        a0 += v[it].x * v[it].x;
        a1 += v[it].y * v[it].y;
        a2 += v[it].z * v[it].z;
        a3 += v[it].w * v[it].w;
    }
    // reduce over the 4 channel-groups in this wave (lanes j, j+16, j+32, j+48)
    a0 += __shfl_xor(a0, 16, 64); a0 += __shfl_xor(a0, 32, 64);
    a1 += __shfl_xor(a1, 16, 64); a1 += __shfl_xor(a1, 32, 64);
    a2 += __shfl_xor(a2, 16, 64); a2 += __shfl_xor(a2, 32, 64);
    a3 += __shfl_xor(a3, 16, 64); a3 += __shfl_xor(a3, 32, 64);
    if (lane < 16) {
        sP[w][4 * j + 0] = a0;
        sP[w][4 * j + 1] = a1;
        sP[w][4 * j + 2] = a2;
        sP[w][4 * j + 3] = a3;
    }
    __syncthreads();

    // ---- per-l scalars (wave 0): x2 -> gamma -> a1[l] = 2*gamma*inv1/G
    if (t < TL) {
        const float x2   = sP[0][t] + sP[1][t] + sP[2][t] + sP[3][t];
        const float inv1 = 1.0f / (1.0f + x2);
        const float xk2  = 4.0f * x2 * inv1 * inv1;           // sum_c xK^2
        const float g    = rsqrtf(fmaxf(1.0f - xk2, 1e-7f));  // gamma
        float G = g;                                          // sum over 4-window
        G += __shfl_xor(G, 1, 64);
        G += __shfl_xor(G, 2, 64);
        sA1[t] = 2.0f * g * inv1 / G;
    }
    __syncthreads();

    // ---- mK per (channel, output j) fully in registers
    const float c0 = sA1[4 * j + 0];
    const float c1 = sA1[4 * j + 1];
    const float c2 = sA1[4 * j + 2];
    const float c3 = sA1[4 * j + 3];
    float mk[16];
    float q = 0.f;                     // partial sum_c mK^2 for output j
    #pragma unroll
    for (int it = 0; it < 16; ++it) {
        mk[it] = v[it].x * c0 + v[it].y * c1 + v[it].z * c2 + v[it].w * c3;
        q += mk[it] * mk[it];
    }
    q += __shfl_xor(q, 16, 64); q += __shfl_xor(q, 32, 64);
    if (lane < 16) sQ[w][j] = q;
    __syncthreads();
    if (t < OT) {
        const float m2 = sQ[0][t] + sQ[1][t] + sQ[2][t] + sQ[3][t];
        sInvm[t] = 1.0f / (1.0f + sqrtf(fmaxf(1.0f - m2, 1e-7f)));
    }
    __syncthreads();

    // ---- scale + store: per wave, 4 rows x 64 B contiguous segments
    const float s = sInvm[j];
    float* op = out + (size_t)(b * C_) * OL_ + (size_t)otile * OT + j;
    #pragma unroll
    for (int it = 0; it < 16; ++it) {
        op[(size_t)(it * 16 + rbase) * OL_] = mk[it] * s;
    }
}

extern "C" void kernel_launch(void* const* d_in, const int* in_sizes, int n_in,
                              void* d_out, int out_size, void* d_ws, size_t ws_size,
                              hipStream_t stream) {
    const float* x = (const float*)d_in[0];
    float* out = (float*)d_out;
    dim3 grid(OL_ / OT, B_);   // 256 o-tiles x 16 batches
    havgpool_hyp_kernel<<<grid, 256, 0, stream>>>(x, out);
}

// Round 4
// 349.687 us; speedup vs baseline: 1.1041x; 1.0915x over previous
//
#include <hip/hip_runtime.h>
#include <stdint.h>

// Reference: B=16, C=256, L=16384, K=S=4 -> OL=4096. fp32 in, fp32 out.
// Decomposition: block = (b, 128 consecutive l / 32 outputs). Thread t owns
// output j = t&31 (l-quad 4j..4j+3) for 16 channels -> window math fully in
// registers; only two tiny scalar reductions cross threads.
#define B_      16
#define C_      256
#define L_      16384
#define OL_     4096
#define OT      32     // outputs per block
#define TL      128    // input l per block (OT*4)
#define NTHR    512
#define OTILES  (OL_ / OT)   // 128

typedef float f4 __attribute__((ext_vector_type(4)));

__global__ __launch_bounds__(NTHR, 4)
void havgpool_hyp_kernel(const float* __restrict__ x, float* __restrict__ out) {
    __shared__ float sP[8][TL];    // per-wave sum_c(x^2) partials (4 KiB)
    __shared__ float sA1[TL];      // per-l combine coefficient
    __shared__ float sQ[8][OT];    // per-wave mK2 partials (1 KiB)
    __shared__ float sInvm[OT];    // per-o final scale

    const int t     = threadIdx.x;
    const int bid   = blockIdx.x;          // 0..2047, otile fastest
    const int otile = bid & (OTILES - 1);  // 0..127
    const int b     = bid >> 7;            // 0..15
    const int j     = t & 31;              // output / l-quad index
    const int rbase = t >> 5;              // channel-group 0..15
    const int lane  = t & 63;
    const int w     = t >> 6;              // wave 0..7

    // ---- Load 16 channels x 4 l into registers; squares accumulated in flight.
    // Per wave-load instruction: 2 rows x 512 B contiguous segments.
    const float* src = x + ((size_t)b * C_ * L_ + (size_t)otile * TL + 4 * j);
    f4 v[16];
    float a0 = 0.f, a1 = 0.f, a2 = 0.f, a3 = 0.f;
    #pragma unroll
    for (int it = 0; it < 16; ++it) {
        v[it] = __builtin_nontemporal_load((const f4*)(src + (size_t)(it * 16 + rbase) * L_));
        a0 += v[it].x * v[it].x;
        a1 += v[it].y * v[it].y;
        a2 += v[it].z * v[it].z;
        a3 += v[it].w * v[it].w;
    }
    // combine the two channel-groups in this wave (lanes j and j+32)
    a0 += __shfl_xor(a0, 32, 64);
    a1 += __shfl_xor(a1, 32, 64);
    a2 += __shfl_xor(a2, 32, 64);
    a3 += __shfl_xor(a3, 32, 64);
    if (lane < 32) {
        sP[w][4 * j + 0] = a0;
        sP[w][4 * j + 1] = a1;
        sP[w][4 * j + 2] = a2;
        sP[w][4 * j + 3] = a3;
    }
    __syncthreads();

    // ---- per-l scalars (waves 0-1): x2 -> gamma -> a1[l] = 2*gamma*inv1/G
    if (t < TL) {
        float x2 = 0.f;
        #pragma unroll
        for (int k = 0; k < 8; ++k) x2 += sP[k][t];          // stride-1: conflict-free
        const float inv1 = 1.0f / (1.0f + x2);
        const float xk2  = 4.0f * x2 * inv1 * inv1;          // sum_c xK^2
        const float g    = rsqrtf(fmaxf(1.0f - xk2, 1e-7f)); // gamma
        float G = g;                                         // sum over 4-window
        G += __shfl_xor(G, 1, 64);
        G += __shfl_xor(G, 2, 64);
        sA1[t] = 2.0f * g * inv1 / G;
    }
    __syncthreads();

    // ---- mK per (channel, output j) fully in registers
    const float c0 = sA1[4 * j + 0];
    const float c1 = sA1[4 * j + 1];
    const float c2 = sA1[4 * j + 2];
    const float c3 = sA1[4 * j + 3];
    float mk[16];
    float q = 0.f;                     // partial sum_c mK^2 for output j
    #pragma unroll
    for (int it = 0; it < 16; ++it) {
        mk[it] = v[it].x * c0 + v[it].y * c1 + v[it].z * c2 + v[it].w * c3;
        q += mk[it] * mk[it];
    }
    q += __shfl_xor(q, 32, 64);
    if (lane < 32) sQ[w][j] = q;
    __syncthreads();
    if (t < OT) {
        float m2 = 0.f;
        #pragma unroll
        for (int k = 0; k < 8; ++k) m2 += sQ[k][t];
        sInvm[t] = 1.0f / (1.0f + sqrtf(fmaxf(1.0f - m2, 1e-7f)));
    }
    __syncthreads();

    // ---- scale + store: per wave-store instruction, 2 rows x 128 B full lines
    const float s = sInvm[j];
    float* op = out + (size_t)(b * C_) * OL_ + (size_t)otile * OT + j;
    #pragma unroll
    for (int it = 0; it < 16; ++it) {
        __builtin_nontemporal_store(mk[it] * s, op + (size_t)(it * 16 + rbase) * OL_);
    }
}

extern "C" void kernel_launch(void* const* d_in, const int* in_sizes, int n_in,
                              void* d_out, int out_size, void* d_ws, size_t ws_size,
                              hipStream_t stream) {
    const float* x = (const float*)d_in[0];
    float* out = (float*)d_out;
    havgpool_hyp_kernel<<<dim3(OTILES * B_), NTHR, 0, stream>>>(x, out);
}